// Round 6
// baseline (595.827 us; speedup 1.0000x reference)
//
#include <hip/hip_runtime.h>

// PGA G(3,0,1) GeometricBilinear — bf16 MFMA, persistent 4-tile schedule (R6).
// P = 16384 positions. CIN=64, 2H=256, H=128, COUT=64, 16 blades.
//
// Blade-pair packing (verified R4): for pair e (blades 2e, 2e+1):
//   X1[row = e*16+pos][k], k = s*64+i -> x[p, i, 2e+s]  (bf16 LDS, 256B rows, XOR swz)
//   even j=2e:  K=64;  odd j=2e+1: K=128 — weights pre-packed in d_ws (prep_w, as R4).
// MFMA 16x16x32: A=Wj (m=o), B=X1 (n=pos). Wave w owns of-pair (f,f+4):
// lane holds h[c] and h[c+64] -> GP/join fully in-register (verified R4).
// X2[row = e2*16+pos][k2 = s*128+cc] (512B rows) -> phase-2 MFMA -> LDS epilogue.
//
// R6 fix: epilogue v1 store address was (raw ^ swz) + 16 — carry out of bit4
// broke the swizzle for odd positions (absmax 15.3). Now (raw + 16) ^ swz.
// Rule: XOR-swizzle applies to the FINAL raw address; never add after XOR.

namespace {

constexpr int popc4(int v){int c=0;while(v){c+=v&1;v>>=1;}return c;}
constexpr float sgnf(int a,int b){int s=0;a>>=1;while(a){s+=popc4(a&b);a>>=1;}return (s&1)?-1.f:1.f;}

struct Tabs { float gp[16][16]; float jn[16][16]; };
constexpr Tabs mk(){
    Tabs t{};
    for(int a=0;a<16;a++)for(int b=0;b<16;b++){
        t.gp[a][b] = (a&b&1) ? 0.f : sgnf(a,b);
        if((a|b)==15){
            const int k = a&b;
            t.jn[a][b] = sgnf(a,15^a)*sgnf(b,15^b)*sgnf(15^a,15^b)*sgnf(k,15^k);
        } else t.jn[a][b] = 0.f;
    }
    return t;
}
constexpr Tabs TB = mk();
constexpr int GE[8] = {0,1,1,2,1,2,2,3};  // fallback kernel

constexpr int OFF1(int j){ return (j>>1)*49152 + ((j&1)?16384:0); }   // w1b: even 256*64, odd 256*128
constexpr int OFF2(int j){ return (j>>1)*24576 + ((j&1)?8192:0);  }   // w2b: even 64*128, odd 64*256
constexpr int W1B_ELEMS = 393216;
constexpr int W2B_ELEMS = 196608;

typedef short bf16x8 __attribute__((ext_vector_type(8)));
typedef float f32x4  __attribute__((ext_vector_type(4)));

__device__ inline unsigned short f2bf(float f){
    unsigned int u = __float_as_uint(f);
    u = u + 0x7fffu + ((u >> 16) & 1u);
    return (unsigned short)(u >> 16);
}
__device__ inline unsigned pack2(float a, float b){
    return (unsigned)f2bf(a) | ((unsigned)f2bf(b) << 16);
}

} // namespace

// ---------------- weight prep (identical to R4, verified) --------------------
__global__ void prep_w(const float* __restrict__ w1, const float* __restrict__ w2,
                       unsigned short* __restrict__ w1b, unsigned short* __restrict__ w2b)
{
    int idx = blockIdx.x * 256 + threadIdx.x;
    if (idx < W1B_ELEMS) {
        const int p = idx / 49152, rem = idx - p*49152;
        float v;
        if (rem < 16384) {                       // even j: [256 o][64 k]
            const int j = 2*p, o = rem >> 6, k = rem & 63;
            v = w1[(o*64 + k)*9 + __popc(j)];
        } else {                                 // odd j: [256 o][128 k]
            const int j = 2*p + 1, r2 = rem - 16384, o = r2 >> 7, k = r2 & 127;
            const int g = __popc(j), i = k & 63, r = (k < 64) ? g + 4 : g;
            v = w1[(o*64 + i)*9 + r];
        }
        w1b[idx] = f2bf(v);
    } else {
        idx -= W1B_ELEMS;
        if (idx < W2B_ELEMS) {
            const int p = idx / 24576, rem = idx - p*24576;
            float v;
            if (rem < 8192) {                    // even j: [64 o][128 k]
                const int j = 2*p, o = rem >> 7, k = rem & 127;
                v = w2[(o*128 + k)*9 + __popc(j)];
            } else {                             // odd j: [64 o][256 k]
                const int j = 2*p + 1, r2 = rem - 8192, o = r2 >> 8, k = r2 & 255;
                const int g = __popc(j), i = k & 127, r = (k < 128) ? g + 4 : g;
                v = w2[(o*128 + i)*9 + r];
            }
            w2b[idx] = f2bf(v);
        }
    }
}

// ---------------- fused MFMA kernel: 256 blocks x 4 tiles x 16 pos -----------
__global__ __launch_bounds__(512, 2) void gb_mfma(
    const float* __restrict__ x, const float* __restrict__ ref,
    const float* __restrict__ b1, const float* __restrict__ b2,
    const unsigned short* __restrict__ w1b, const unsigned short* __restrict__ w2b,
    float* __restrict__ out)
{
    __shared__ __attribute__((aligned(16))) char lds[131072]; // X1 dbuf 2x32KB @0, X2/epi 64KB @65536
    __shared__ float lref[2][16];

    const int t  = threadIdx.x;
    const int bid = blockIdx.x;
    const int w  = t >> 6;
    const int l  = t & 63;
    const int ln = l & 15;
    const int lh = l >> 4;
    const int swz = (ln & 7) << 4;

    const int f0 = (w < 4) ? w : w + 4;
    const int oA = f0*16 + ln;
    const int oB = (f0+4)*16 + ln;
    const int jh = w >> 2;
    const int o2base = (w & 3) * 16;
    const int pc0 = (w < 4) ? w*16 : 64 + (w - 4)*16;

    const int spos = t >> 5;          // staging: thread <-> (pos, i-pair)
    const int si0  = (t & 31) * 2;

    // ---- prologue: stage tile 0 into buffer 0 ----
    {
        const float* gsrc = x + ((long)(bid*64 + spos))*1024 + si0*16;
        float4 v[8];
        #pragma unroll
        for (int a = 0; a < 8; ++a) v[a] = *(const float4*)(gsrc + a*4);
        char* Xb = lds;
        #pragma unroll
        for (int b = 0; b < 16; ++b) {
            const int e = b >> 1, s = b & 1;
            const float va = ((const float*)&v[b>>2])[b&3];
            const float vb = ((const float*)&v[4 + (b>>2)])[b&3];
            *(unsigned*)(Xb + ((((e*16 + spos) << 8) + (s << 7) + (si0 << 1)) ^ ((spos&7)<<4))) = pack2(va, vb);
        }
        if (t < 16) lref[0][t] = ref[((long)(bid*64 + t))*16 + 15];
    }
    __syncthreads();

    for (int tt = 0; tt < 4; ++tt) {
        const int cur = tt & 1;
        const int p0t = bid*64 + tt*16;
        const char* Xb = lds + cur*32768;
        char* X2 = lds + 65536;

        // ---- phase 1 ----
        f32x4 acc[16][2];
        #pragma unroll
        for (int j = 0; j < 16; ++j) { acc[j][0] = (f32x4)0.f; acc[j][1] = (f32x4)0.f; }

        #pragma unroll
        for (int j = 0; j < 16; ++j) {
            const int e  = j >> 1;
            const int Kj = (j & 1) ? 128 : 64;
            const unsigned short* Aj = w1b + OFF1(j);
            #pragma unroll
            for (int kf = 0; kf < ((j & 1) ? 4 : 2); ++kf) {
                const int k0 = kf*32 + lh*8;
                const bf16x8 bx = *(const bf16x8*)(Xb + ((((e*16 + ln) << 8) + (k0 << 1)) ^ swz));
                const bf16x8 a0 = *(const bf16x8*)(Aj + oA*Kj + k0);
                const bf16x8 a1 = *(const bf16x8*)(Aj + oB*Kj + k0);
                acc[j][0] = __builtin_amdgcn_mfma_f32_16x16x32_bf16(a0, bx, acc[j][0], 0, 0, 0);
                acc[j][1] = __builtin_amdgcn_mfma_f32_16x16x32_bf16(a1, bx, acc[j][1], 0, 0, 0);
            }
        }
        {
            #pragma unroll
            for (int r = 0; r < 4; ++r) {
                acc[0][0][r] += b1[f0*16     + lh*4 + r];
                acc[0][1][r] += b1[(f0+4)*16 + lh*4 + r];
            }
        }

        // ---- products in-register ----
        f32x4 prod[16];
        #pragma unroll
        for (int j = 0; j < 16; ++j) prod[j] = (f32x4)0.f;
        if (w < 4) {
            #pragma unroll
            for (int A = 0; A < 16; ++A)
                #pragma unroll
                for (int B = 0; B < 16; ++B) {
                    constexpr auto& G = TB.gp;
                    if (G[A][B] > 0.f)      prod[A ^ B] += acc[A][0] * acc[B][1];
                    else if (G[A][B] < 0.f) prod[A ^ B] -= acc[A][0] * acc[B][1];
                }
        } else {
            #pragma unroll
            for (int A = 0; A < 16; ++A)
                #pragma unroll
                for (int B = 0; B < 16; ++B) {
                    constexpr auto& J = TB.jn;
                    if (J[A][B] > 0.f)      prod[A & B] += acc[A][0] * acc[B][1];
                    else if (J[A][B] < 0.f) prod[A & B] -= acc[A][0] * acc[B][1];
                }
            const float rv = lref[cur][ln];
            #pragma unroll
            for (int j = 0; j < 16; ++j) prod[j] *= rv;
        }

        // ---- write prod -> X2 (4B pairs along cc) ----
        #pragma unroll
        for (int e2 = 0; e2 < 8; ++e2)
            #pragma unroll
            for (int s = 0; s < 2; ++s)
                #pragma unroll
                for (int rp = 0; rp < 4; rp += 2) {
                    const int cc = pc0 + lh*4 + rp;
                    *(unsigned*)(X2 + ((((e2*16 + ln) << 9) + (s << 8) + (cc << 1)) ^ swz)) =
                        pack2(prod[2*e2 + s][rp], prod[2*e2 + s][rp + 1]);
                }
        __syncthreads();   // X2 visible to all waves

        // ---- phase 2 (+ overlapped staging of tile tt+1) ----
        const bool do_stage = (tt < 3);
        float4 sv[8];
        float rnext = 0.f;
        if (do_stage) {
            const float* gsrc = x + ((long)(p0t + 16 + spos))*1024 + si0*16;
            #pragma unroll
            for (int a = 0; a < 8; ++a) sv[a] = *(const float4*)(gsrc + a*4);
            if (t < 16) rnext = ref[((long)(p0t + 16 + t))*16 + 15];
        }

        f32x4 acc2[8];
        #pragma unroll
        for (int jj = 0; jj < 8; ++jj) acc2[jj] = (f32x4)0.f;

        #pragma unroll
        for (int jj = 0; jj < 8; ++jj) {
            const int j2 = jh*8 + jj;
            const int e2 = j2 >> 1;
            const int K2 = (j2 & 1) ? 256 : 128;
            const unsigned short* A2 = w2b + OFF2(j2);
            #pragma unroll
            for (int kf = 0; kf < ((j2 & 1) ? 8 : 4); ++kf) {
                const int k0 = kf*32 + lh*8;
                const bf16x8 bx = *(const bf16x8*)(X2 + ((((e2*16 + ln) << 9) + (k0 << 1)) ^ swz));
                const bf16x8 a  = *(const bf16x8*)(A2 + (o2base + ln)*K2 + k0);
                acc2[jj] = __builtin_amdgcn_mfma_f32_16x16x32_bf16(a, bx, acc2[jj], 0, 0, 0);
            }
        }
        if (jh == 0) {
            #pragma unroll
            for (int r = 0; r < 4; ++r) acc2[0][r] += b2[o2base + lh*4 + r];
        }

        if (do_stage) {
            char* Xn = lds + (cur ^ 1)*32768;
            #pragma unroll
            for (int b = 0; b < 16; ++b) {
                const int e = b >> 1, s = b & 1;
                const float va = ((const float*)&sv[b>>2])[b&3];
                const float vb = ((const float*)&sv[4 + (b>>2)])[b&3];
                *(unsigned*)(Xn + ((((e*16 + spos) << 8) + (s << 7) + (si0 << 1)) ^ ((spos&7)<<4))) = pack2(va, vb);
            }
            if (t < 16) lref[cur ^ 1][t] = rnext;
        }
        __syncthreads();   // phase-2 X2 reads done; X1[nxt] staged

        // ---- epilogue: acc2 -> LDS (X2 region, fp32) -> coalesced stores ----
        {
            char* L2c = lds + 65536;
            #pragma unroll
            for (int r = 0; r < 4; ++r) {
                const int o2 = o2base + lh*4 + r;
                const int raw0 = (ln << 12) + (o2 << 6) + (jh << 5);
                *(float4*)(L2c + (raw0 ^ swz)) =
                    make_float4(acc2[0][r], acc2[1][r], acc2[2][r], acc2[3][r]);
                *(float4*)(L2c + ((raw0 + 16) ^ swz)) =
                    make_float4(acc2[4][r], acc2[5][r], acc2[6][r], acc2[7][r]);
            }
        }
        __syncthreads();
        {
            const char* L2c = lds + 65536;
            #pragma unroll
            for (int it = 0; it < 8; ++it) {
                const int idx = it*512 + t;
                const int pos = idx >> 8, off = idx & 255;
                const float4 vv = *(const float4*)(L2c + (((pos << 12) + (off << 4)) ^ ((pos&7)<<4)));
                *(float4*)(out + ((long)(p0t + pos))*1024 + off*4) = vv;
            }
        }
        __syncthreads();   // LDS free for next tile
    }
}

// ---------------- fp32 fallback (verified R3) --------------------------------
__global__ __launch_bounds__(256, 1) void gb_fused_f32(
    const float* __restrict__ x, const float* __restrict__ ref,
    const float* __restrict__ w1, const float* __restrict__ b1,
    const float* __restrict__ w2, const float* __restrict__ b2,
    float* __restrict__ out)
{
    __shared__ float lds[16384];
    __shared__ float lrefs[8];
    const int t = threadIdx.x;
    const int p0 = blockIdx.x * 8;
    {
        const float4* xg = reinterpret_cast<const float4*>(x) + (size_t)p0 * 256;
        float4* xl = reinterpret_cast<float4*>(lds);
        #pragma unroll
        for (int r = 0; r < 8; ++r) xl[r*256 + t] = xg[r*256 + t];
        if (t < 8) lrefs[t] = ref[(p0 + t)*16 + 15];
    }
    __syncthreads();
    const int c    = t & 127;
    const int half = t >> 7;
    const int ca   = (c < 64) ? c : (c + 64);
    const int cb   = ca + 64;
    float acc[4][2][16];
    #pragma unroll
    for (int q = 0; q < 4; ++q)
        #pragma unroll
        for (int s = 0; s < 2; ++s)
            #pragma unroll
            for (int j = 0; j < 16; ++j) acc[q][s][j] = 0.f;
    for (int i = 0; i < 64; ++i) {
        float wa[9], wb[9];
        #pragma unroll
        for (int r = 0; r < 9; ++r) { wa[r] = w1[(ca*64+i)*9 + r]; wb[r] = w1[(cb*64+i)*9 + r]; }
        #pragma unroll
        for (int q = 0; q < 4; ++q) {
            const float* xv = lds + (half*4 + q)*1024 + i*16;
            float xr[16];
            #pragma unroll
            for (int j4 = 0; j4 < 4; ++j4) {
                const float4 v = *reinterpret_cast<const float4*>(xv + 4*j4);
                xr[4*j4+0]=v.x; xr[4*j4+1]=v.y; xr[4*j4+2]=v.z; xr[4*j4+3]=v.w;
            }
            #pragma unroll
            for (int e = 0; e < 8; ++e) {
                const int ge = GE[e];
                const float xe = xr[2*e], xo = xr[2*e+1];
                acc[q][0][2*e]   += wa[ge]   * xe;
                acc[q][0][2*e+1] += wa[ge+1] * xo;
                acc[q][0][2*e+1] += wa[ge+5] * xe;
                acc[q][1][2*e]   += wb[ge]   * xe;
                acc[q][1][2*e+1] += wb[ge+1] * xo;
                acc[q][1][2*e+1] += wb[ge+5] * xe;
            }
        }
    }
    {
        const float ba = b1[ca], bb = b1[cb];
        #pragma unroll
        for (int q = 0; q < 4; ++q) { acc[q][0][0] += ba; acc[q][1][0] += bb; }
    }
    __syncthreads();
    #pragma unroll
    for (int q = 0; q < 4; ++q) {
        float prod[16];
        #pragma unroll
        for (int j = 0; j < 16; ++j) prod[j] = 0.f;
        if (c < 64) {
            #pragma unroll
            for (int A = 0; A < 16; ++A)
                #pragma unroll
                for (int B = 0; B < 16; ++B)
                    if (TB.gp[A][B] != 0.f)
                        prod[A ^ B] += TB.gp[A][B] * acc[q][0][A] * acc[q][1][B];
        } else {
            #pragma unroll
            for (int A = 0; A < 16; ++A)
                #pragma unroll
                for (int B = 0; B < 16; ++B)
                    if (TB.jn[A][B] != 0.f)
                        prod[A & B] += TB.jn[A][B] * acc[q][0][A] * acc[q][1][B];
            const float rp = lrefs[half*4 + q];
            #pragma unroll
            for (int j = 0; j < 16; ++j) prod[j] *= rp;
        }
        const int pos = half*4 + q;
        #pragma unroll
        for (int j4 = 0; j4 < 4; ++j4)
            *reinterpret_cast<float4*>(&lds[(pos*4 + j4)*512 + c*4]) =
                make_float4(prod[4*j4], prod[4*j4+1], prod[4*j4+2], prod[4*j4+3]);
    }
    __syncthreads();
    const int o    = t & 63;
    const int slot = t >> 6;
    float oacc[2][16];
    #pragma unroll
    for (int e2 = 0; e2 < 2; ++e2)
        #pragma unroll
        for (int j = 0; j < 16; ++j) oacc[e2][j] = 0.f;
    for (int i = 0; i < 128; ++i) {
        float wv[9];
        #pragma unroll
        for (int r = 0; r < 9; ++r) wv[r] = w2[(o*128+i)*9 + r];
        #pragma unroll
        for (int e2 = 0; e2 < 2; ++e2) {
            const int pos = slot*2 + e2;
            float xr[16];
            #pragma unroll
            for (int j4 = 0; j4 < 4; ++j4) {
                const float4 v = *reinterpret_cast<const float4*>(&lds[(pos*4 + j4)*512 + i*4]);
                xr[4*j4+0]=v.x; xr[4*j4+1]=v.y; xr[4*j4+2]=v.z; xr[4*j4+3]=v.w;
            }
            #pragma unroll
            for (int e = 0; e < 8; ++e) {
                const int ge = GE[e];
                oacc[e2][2*e]   += wv[ge]   * xr[2*e];
                oacc[e2][2*e+1] += wv[ge+1] * xr[2*e+1];
                oacc[e2][2*e+1] += wv[ge+5] * xr[2*e];
            }
        }
    }
    {
        const float bo = b2[o];
        #pragma unroll
        for (int e2 = 0; e2 < 2; ++e2) {
            oacc[e2][0] += bo;
            const int pos = p0 + slot*2 + e2;
            float* og = out + (size_t)pos*1024 + o*16;
            #pragma unroll
            for (int j4 = 0; j4 < 4; ++j4)
                *reinterpret_cast<float4*>(og + 4*j4) =
                    make_float4(oacc[e2][4*j4], oacc[e2][4*j4+1],
                                oacc[e2][4*j4+2], oacc[e2][4*j4+3]);
        }
    }
}

extern "C" void kernel_launch(void* const* d_in, const int* in_sizes, int n_in,
                              void* d_out, int out_size, void* d_ws, size_t ws_size,
                              hipStream_t stream)
{
    const float* x  = (const float*)d_in[0];
    const float* rf = (const float*)d_in[1];
    const float* w1 = (const float*)d_in[2];
    const float* b1 = (const float*)d_in[3];
    const float* w2 = (const float*)d_in[4];
    const float* b2 = (const float*)d_in[5];
    float* out = (float*)d_out;

    const size_t need = (size_t)(W1B_ELEMS + W2B_ELEMS) * sizeof(unsigned short);
    if (ws_size >= need) {
        unsigned short* w1b = (unsigned short*)d_ws;
        unsigned short* w2b = w1b + W1B_ELEMS;
        prep_w<<<(W1B_ELEMS + W2B_ELEMS)/256, 256, 0, stream>>>(w1, w2, w1b, w2b);
        gb_mfma<<<256, 512, 0, stream>>>(x, rf, b1, b2, w1b, w2b, out);
    } else {
        gb_fused_f32<<<2048, 256, 0, stream>>>(x, rf, w1, b1, w2, b2, out);
    }
}

// Round 7
// 595.412 us; speedup vs baseline: 1.0007x; 1.0007x over previous
//
#include <hip/hip_runtime.h>

// PGA G(3,0,1) GeometricBilinear — bf16 MFMA, persistent 4-tile schedule (R7).
// P = 16384 positions. CIN=64, 2H=256, H=128, COUT=64, 16 blades.
//
// Blade-pair packing (verified R4): for pair e (blades 2e, 2e+1):
//   X1[row = e*16+pos][k], k = s*64+i -> x[p, i, 2e+s]  (bf16 LDS, 256B rows, XOR swz)
//   even j=2e:  K=64;  odd j=2e+1: K=128 — weights pre-packed in d_ws (prep_w).
// MFMA 16x16x32: A=Wj (m=o), B=X1 (n=pos). Wave w owns of-pair (f,f+4):
// lane holds h[c] and h[c+64] -> GP/join fully in-register (verified R4).
// X2[row = e2*16+pos][k2 = s*128+cc] (512B rows) -> phase-2 MFMA -> LDS epilogue.
//
// R6 fix (kept): epilogue v1 address is (raw + 16) ^ swz, never (raw^swz)+16.
// R7 change: __launch_bounds__(512,1). R6's (512,2) capped the unified
// VGPR+AGPR file at ~256/wave; acc[16][2]=128 AGPR + sv[8] prefetch + dbuf
// addressing spilled (FETCH 772MB / WRITE 437MB scratch traffic, 596us).
// Occupancy is 1 block/CU regardless (128KB LDS), so the cap bought nothing.
// With 512 regs/wave the compiler can also pipeline weight loads deeply.

namespace {

constexpr int popc4(int v){int c=0;while(v){c+=v&1;v>>=1;}return c;}
constexpr float sgnf(int a,int b){int s=0;a>>=1;while(a){s+=popc4(a&b);a>>=1;}return (s&1)?-1.f:1.f;}

struct Tabs { float gp[16][16]; float jn[16][16]; };
constexpr Tabs mk(){
    Tabs t{};
    for(int a=0;a<16;a++)for(int b=0;b<16;b++){
        t.gp[a][b] = (a&b&1) ? 0.f : sgnf(a,b);
        if((a|b)==15){
            const int k = a&b;
            t.jn[a][b] = sgnf(a,15^a)*sgnf(b,15^b)*sgnf(15^a,15^b)*sgnf(k,15^k);
        } else t.jn[a][b] = 0.f;
    }
    return t;
}
constexpr Tabs TB = mk();
constexpr int GE[8] = {0,1,1,2,1,2,2,3};  // fallback kernel

constexpr int OFF1(int j){ return (j>>1)*49152 + ((j&1)?16384:0); }   // w1b: even 256*64, odd 256*128
constexpr int OFF2(int j){ return (j>>1)*24576 + ((j&1)?8192:0);  }   // w2b: even 64*128, odd 64*256
constexpr int W1B_ELEMS = 393216;
constexpr int W2B_ELEMS = 196608;

typedef short bf16x8 __attribute__((ext_vector_type(8)));
typedef float f32x4  __attribute__((ext_vector_type(4)));

__device__ inline unsigned short f2bf(float f){
    unsigned int u = __float_as_uint(f);
    u = u + 0x7fffu + ((u >> 16) & 1u);
    return (unsigned short)(u >> 16);
}
__device__ inline unsigned pack2(float a, float b){
    return (unsigned)f2bf(a) | ((unsigned)f2bf(b) << 16);
}

} // namespace

// ---------------- weight prep (identical to R4, verified) --------------------
__global__ void prep_w(const float* __restrict__ w1, const float* __restrict__ w2,
                       unsigned short* __restrict__ w1b, unsigned short* __restrict__ w2b)
{
    int idx = blockIdx.x * 256 + threadIdx.x;
    if (idx < W1B_ELEMS) {
        const int p = idx / 49152, rem = idx - p*49152;
        float v;
        if (rem < 16384) {                       // even j: [256 o][64 k]
            const int j = 2*p, o = rem >> 6, k = rem & 63;
            v = w1[(o*64 + k)*9 + __popc(j)];
        } else {                                 // odd j: [256 o][128 k]
            const int j = 2*p + 1, r2 = rem - 16384, o = r2 >> 7, k = r2 & 127;
            const int g = __popc(j), i = k & 63, r = (k < 64) ? g + 4 : g;
            v = w1[(o*64 + i)*9 + r];
        }
        w1b[idx] = f2bf(v);
    } else {
        idx -= W1B_ELEMS;
        if (idx < W2B_ELEMS) {
            const int p = idx / 24576, rem = idx - p*24576;
            float v;
            if (rem < 8192) {                    // even j: [64 o][128 k]
                const int j = 2*p, o = rem >> 7, k = rem & 127;
                v = w2[(o*128 + k)*9 + __popc(j)];
            } else {                             // odd j: [64 o][256 k]
                const int j = 2*p + 1, r2 = rem - 8192, o = r2 >> 8, k = r2 & 255;
                const int g = __popc(j), i = k & 127, r = (k < 128) ? g + 4 : g;
                v = w2[(o*128 + i)*9 + r];
            }
            w2b[idx] = f2bf(v);
        }
    }
}

// ---------------- fused MFMA kernel: 256 blocks x 4 tiles x 16 pos -----------
__global__ __launch_bounds__(512, 1) void gb_mfma(
    const float* __restrict__ x, const float* __restrict__ ref,
    const float* __restrict__ b1, const float* __restrict__ b2,
    const unsigned short* __restrict__ w1b, const unsigned short* __restrict__ w2b,
    float* __restrict__ out)
{
    __shared__ __attribute__((aligned(16))) char lds[131072]; // X1 dbuf 2x32KB @0, X2/epi 64KB @65536
    __shared__ float lref[2][16];

    const int t  = threadIdx.x;
    const int bid = blockIdx.x;
    const int w  = t >> 6;
    const int l  = t & 63;
    const int ln = l & 15;
    const int lh = l >> 4;
    const int swz = (ln & 7) << 4;

    const int f0 = (w < 4) ? w : w + 4;
    const int oA = f0*16 + ln;
    const int oB = (f0+4)*16 + ln;
    const int jh = w >> 2;
    const int o2base = (w & 3) * 16;
    const int pc0 = (w < 4) ? w*16 : 64 + (w - 4)*16;

    const int spos = t >> 5;          // staging: thread <-> (pos, i-pair)
    const int si0  = (t & 31) * 2;

    // ---- prologue: stage tile 0 into buffer 0 ----
    {
        const float* gsrc = x + ((long)(bid*64 + spos))*1024 + si0*16;
        float4 v[8];
        #pragma unroll
        for (int a = 0; a < 8; ++a) v[a] = *(const float4*)(gsrc + a*4);
        char* Xb = lds;
        #pragma unroll
        for (int b = 0; b < 16; ++b) {
            const int e = b >> 1, s = b & 1;
            const float va = ((const float*)&v[b>>2])[b&3];
            const float vb = ((const float*)&v[4 + (b>>2)])[b&3];
            *(unsigned*)(Xb + ((((e*16 + spos) << 8) + (s << 7) + (si0 << 1)) ^ ((spos&7)<<4))) = pack2(va, vb);
        }
        if (t < 16) lref[0][t] = ref[((long)(bid*64 + t))*16 + 15];
    }
    __syncthreads();

    for (int tt = 0; tt < 4; ++tt) {
        const int cur = tt & 1;
        const int p0t = bid*64 + tt*16;
        const char* Xb = lds + cur*32768;
        char* X2 = lds + 65536;

        // ---- phase 1 ----
        f32x4 acc[16][2];
        #pragma unroll
        for (int j = 0; j < 16; ++j) { acc[j][0] = (f32x4)0.f; acc[j][1] = (f32x4)0.f; }

        #pragma unroll
        for (int j = 0; j < 16; ++j) {
            const int e  = j >> 1;
            const int Kj = (j & 1) ? 128 : 64;
            const unsigned short* Aj = w1b + OFF1(j);
            #pragma unroll
            for (int kf = 0; kf < ((j & 1) ? 4 : 2); ++kf) {
                const int k0 = kf*32 + lh*8;
                const bf16x8 bx = *(const bf16x8*)(Xb + ((((e*16 + ln) << 8) + (k0 << 1)) ^ swz));
                const bf16x8 a0 = *(const bf16x8*)(Aj + oA*Kj + k0);
                const bf16x8 a1 = *(const bf16x8*)(Aj + oB*Kj + k0);
                acc[j][0] = __builtin_amdgcn_mfma_f32_16x16x32_bf16(a0, bx, acc[j][0], 0, 0, 0);
                acc[j][1] = __builtin_amdgcn_mfma_f32_16x16x32_bf16(a1, bx, acc[j][1], 0, 0, 0);
            }
        }
        {
            #pragma unroll
            for (int r = 0; r < 4; ++r) {
                acc[0][0][r] += b1[f0*16     + lh*4 + r];
                acc[0][1][r] += b1[(f0+4)*16 + lh*4 + r];
            }
        }

        // ---- products in-register ----
        f32x4 prod[16];
        #pragma unroll
        for (int j = 0; j < 16; ++j) prod[j] = (f32x4)0.f;
        if (w < 4) {
            #pragma unroll
            for (int A = 0; A < 16; ++A)
                #pragma unroll
                for (int B = 0; B < 16; ++B) {
                    constexpr auto& G = TB.gp;
                    if (G[A][B] > 0.f)      prod[A ^ B] += acc[A][0] * acc[B][1];
                    else if (G[A][B] < 0.f) prod[A ^ B] -= acc[A][0] * acc[B][1];
                }
        } else {
            #pragma unroll
            for (int A = 0; A < 16; ++A)
                #pragma unroll
                for (int B = 0; B < 16; ++B) {
                    constexpr auto& J = TB.jn;
                    if (J[A][B] > 0.f)      prod[A & B] += acc[A][0] * acc[B][1];
                    else if (J[A][B] < 0.f) prod[A & B] -= acc[A][0] * acc[B][1];
                }
            const float rv = lref[cur][ln];
            #pragma unroll
            for (int j = 0; j < 16; ++j) prod[j] *= rv;
        }

        // ---- write prod -> X2 (4B pairs along cc) ----
        #pragma unroll
        for (int e2 = 0; e2 < 8; ++e2)
            #pragma unroll
            for (int s = 0; s < 2; ++s)
                #pragma unroll
                for (int rp = 0; rp < 4; rp += 2) {
                    const int cc = pc0 + lh*4 + rp;
                    *(unsigned*)(X2 + ((((e2*16 + ln) << 9) + (s << 8) + (cc << 1)) ^ swz)) =
                        pack2(prod[2*e2 + s][rp], prod[2*e2 + s][rp + 1]);
                }
        __syncthreads();   // X2 visible to all waves

        // ---- phase 2 (+ overlapped staging of tile tt+1) ----
        const bool do_stage = (tt < 3);
        float4 sv[8];
        float rnext = 0.f;
        if (do_stage) {
            const float* gsrc = x + ((long)(p0t + 16 + spos))*1024 + si0*16;
            #pragma unroll
            for (int a = 0; a < 8; ++a) sv[a] = *(const float4*)(gsrc + a*4);
            if (t < 16) rnext = ref[((long)(p0t + 16 + t))*16 + 15];
        }

        f32x4 acc2[8];
        #pragma unroll
        for (int jj = 0; jj < 8; ++jj) acc2[jj] = (f32x4)0.f;

        #pragma unroll
        for (int jj = 0; jj < 8; ++jj) {
            const int j2 = jh*8 + jj;
            const int e2 = j2 >> 1;
            const int K2 = (j2 & 1) ? 256 : 128;
            const unsigned short* A2 = w2b + OFF2(j2);
            #pragma unroll
            for (int kf = 0; kf < ((j2 & 1) ? 8 : 4); ++kf) {
                const int k0 = kf*32 + lh*8;
                const bf16x8 bx = *(const bf16x8*)(X2 + ((((e2*16 + ln) << 9) + (k0 << 1)) ^ swz));
                const bf16x8 a  = *(const bf16x8*)(A2 + (o2base + ln)*K2 + k0);
                acc2[jj] = __builtin_amdgcn_mfma_f32_16x16x32_bf16(a, bx, acc2[jj], 0, 0, 0);
            }
        }
        if (jh == 0) {
            #pragma unroll
            for (int r = 0; r < 4; ++r) acc2[0][r] += b2[o2base + lh*4 + r];
        }

        if (do_stage) {
            char* Xn = lds + (cur ^ 1)*32768;
            #pragma unroll
            for (int b = 0; b < 16; ++b) {
                const int e = b >> 1, s = b & 1;
                const float va = ((const float*)&sv[b>>2])[b&3];
                const float vb = ((const float*)&sv[4 + (b>>2)])[b&3];
                *(unsigned*)(Xn + ((((e*16 + spos) << 8) + (s << 7) + (si0 << 1)) ^ ((spos&7)<<4))) = pack2(va, vb);
            }
            if (t < 16) lref[cur ^ 1][t] = rnext;
        }
        __syncthreads();   // phase-2 X2 reads done; X1[nxt] staged

        // ---- epilogue: acc2 -> LDS (X2 region, fp32) -> coalesced stores ----
        {
            char* L2c = lds + 65536;
            #pragma unroll
            for (int r = 0; r < 4; ++r) {
                const int o2 = o2base + lh*4 + r;
                const int raw0 = (ln << 12) + (o2 << 6) + (jh << 5);
                *(float4*)(L2c + (raw0 ^ swz)) =
                    make_float4(acc2[0][r], acc2[1][r], acc2[2][r], acc2[3][r]);
                *(float4*)(L2c + ((raw0 + 16) ^ swz)) =
                    make_float4(acc2[4][r], acc2[5][r], acc2[6][r], acc2[7][r]);
            }
        }
        __syncthreads();
        {
            const char* L2c = lds + 65536;
            #pragma unroll
            for (int it = 0; it < 8; ++it) {
                const int idx = it*512 + t;
                const int pos = idx >> 8, off = idx & 255;
                const float4 vv = *(const float4*)(L2c + (((pos << 12) + (off << 4)) ^ ((pos&7)<<4)));
                *(float4*)(out + ((long)(p0t + pos))*1024 + off*4) = vv;
            }
        }
        __syncthreads();   // LDS free for next tile
    }
}

// ---------------- fp32 fallback (verified R3) --------------------------------
__global__ __launch_bounds__(256, 1) void gb_fused_f32(
    const float* __restrict__ x, const float* __restrict__ ref,
    const float* __restrict__ w1, const float* __restrict__ b1,
    const float* __restrict__ w2, const float* __restrict__ b2,
    float* __restrict__ out)
{
    __shared__ float lds[16384];
    __shared__ float lrefs[8];
    const int t = threadIdx.x;
    const int p0 = blockIdx.x * 8;
    {
        const float4* xg = reinterpret_cast<const float4*>(x) + (size_t)p0 * 256;
        float4* xl = reinterpret_cast<float4*>(lds);
        #pragma unroll
        for (int r = 0; r < 8; ++r) xl[r*256 + t] = xg[r*256 + t];
        if (t < 8) lrefs[t] = ref[(p0 + t)*16 + 15];
    }
    __syncthreads();
    const int c    = t & 127;
    const int half = t >> 7;
    const int ca   = (c < 64) ? c : (c + 64);
    const int cb   = ca + 64;
    float acc[4][2][16];
    #pragma unroll
    for (int q = 0; q < 4; ++q)
        #pragma unroll
        for (int s = 0; s < 2; ++s)
            #pragma unroll
            for (int j = 0; j < 16; ++j) acc[q][s][j] = 0.f;
    for (int i = 0; i < 64; ++i) {
        float wa[9], wb[9];
        #pragma unroll
        for (int r = 0; r < 9; ++r) { wa[r] = w1[(ca*64+i)*9 + r]; wb[r] = w1[(cb*64+i)*9 + r]; }
        #pragma unroll
        for (int q = 0; q < 4; ++q) {
            const float* xv = lds + (half*4 + q)*1024 + i*16;
            float xr[16];
            #pragma unroll
            for (int j4 = 0; j4 < 4; ++j4) {
                const float4 v = *reinterpret_cast<const float4*>(xv + 4*j4);
                xr[4*j4+0]=v.x; xr[4*j4+1]=v.y; xr[4*j4+2]=v.z; xr[4*j4+3]=v.w;
            }
            #pragma unroll
            for (int e = 0; e < 8; ++e) {
                const int ge = GE[e];
                const float xe = xr[2*e], xo = xr[2*e+1];
                acc[q][0][2*e]   += wa[ge]   * xe;
                acc[q][0][2*e+1] += wa[ge+1] * xo;
                acc[q][0][2*e+1] += wa[ge+5] * xe;
                acc[q][1][2*e]   += wb[ge]   * xe;
                acc[q][1][2*e+1] += wb[ge+1] * xo;
                acc[q][1][2*e+1] += wb[ge+5] * xe;
            }
        }
    }
    {
        const float ba = b1[ca], bb = b1[cb];
        #pragma unroll
        for (int q = 0; q < 4; ++q) { acc[q][0][0] += ba; acc[q][1][0] += bb; }
    }
    __syncthreads();
    #pragma unroll
    for (int q = 0; q < 4; ++q) {
        float prod[16];
        #pragma unroll
        for (int j = 0; j < 16; ++j) prod[j] = 0.f;
        if (c < 64) {
            #pragma unroll
            for (int A = 0; A < 16; ++A)
                #pragma unroll
                for (int B = 0; B < 16; ++B)
                    if (TB.gp[A][B] != 0.f)
                        prod[A ^ B] += TB.gp[A][B] * acc[q][0][A] * acc[q][1][B];
        } else {
            #pragma unroll
            for (int A = 0; A < 16; ++A)
                #pragma unroll
                for (int B = 0; B < 16; ++B)
                    if (TB.jn[A][B] != 0.f)
                        prod[A & B] += TB.jn[A][B] * acc[q][0][A] * acc[q][1][B];
            const float rp = lrefs[half*4 + q];
            #pragma unroll
            for (int j = 0; j < 16; ++j) prod[j] *= rp;
        }
        const int pos = half*4 + q;
        #pragma unroll
        for (int j4 = 0; j4 < 4; ++j4)
            *reinterpret_cast<float4*>(&lds[(pos*4 + j4)*512 + c*4]) =
                make_float4(prod[4*j4], prod[4*j4+1], prod[4*j4+2], prod[4*j4+3]);
    }
    __syncthreads();
    const int o    = t & 63;
    const int slot = t >> 6;
    float oacc[2][16];
    #pragma unroll
    for (int e2 = 0; e2 < 2; ++e2)
        #pragma unroll
        for (int j = 0; j < 16; ++j) oacc[e2][j] = 0.f;
    for (int i = 0; i < 128; ++i) {
        float wv[9];
        #pragma unroll
        for (int r = 0; r < 9; ++r) wv[r] = w2[(o*128+i)*9 + r];
        #pragma unroll
        for (int e2 = 0; e2 < 2; ++e2) {
            const int pos = slot*2 + e2;
            float xr[16];
            #pragma unroll
            for (int j4 = 0; j4 < 4; ++j4) {
                const float4 v = *reinterpret_cast<const float4*>(&lds[(pos*4 + j4)*512 + i*4]);
                xr[4*j4+0]=v.x; xr[4*j4+1]=v.y; xr[4*j4+2]=v.z; xr[4*j4+3]=v.w;
            }
            #pragma unroll
            for (int e = 0; e < 8; ++e) {
                const int ge = GE[e];
                oacc[e2][2*e]   += wv[ge]   * xr[2*e];
                oacc[e2][2*e+1] += wv[ge+1] * xr[2*e+1];
                oacc[e2][2*e+1] += wv[ge+5] * xr[2*e];
            }
        }
    }
    {
        const float bo = b2[o];
        #pragma unroll
        for (int e2 = 0; e2 < 2; ++e2) {
            oacc[e2][0] += bo;
            const int pos = p0 + slot*2 + e2;
            float* og = out + (size_t)pos*1024 + o*16;
            #pragma unroll
            for (int j4 = 0; j4 < 4; ++j4)
                *reinterpret_cast<float4*>(og + 4*j4) =
                    make_float4(oacc[e2][4*j4], oacc[e2][4*j4+1],
                                oacc[e2][4*j4+2], oacc[e2][4*j4+3]);
        }
    }
}

extern "C" void kernel_launch(void* const* d_in, const int* in_sizes, int n_in,
                              void* d_out, int out_size, void* d_ws, size_t ws_size,
                              hipStream_t stream)
{
    const float* x  = (const float*)d_in[0];
    const float* rf = (const float*)d_in[1];
    const float* w1 = (const float*)d_in[2];
    const float* b1 = (const float*)d_in[3];
    const float* w2 = (const float*)d_in[4];
    const float* b2 = (const float*)d_in[5];
    float* out = (float*)d_out;

    const size_t need = (size_t)(W1B_ELEMS + W2B_ELEMS) * sizeof(unsigned short);
    if (ws_size >= need) {
        unsigned short* w1b = (unsigned short*)d_ws;
        unsigned short* w2b = w1b + W1B_ELEMS;
        prep_w<<<(W1B_ELEMS + W2B_ELEMS)/256, 256, 0, stream>>>(w1, w2, w1b, w2b);
        gb_mfma<<<256, 512, 0, stream>>>(x, rf, b1, b2, w1b, w2b, out);
    } else {
        gb_fused_f32<<<2048, 256, 0, stream>>>(x, rf, w1, b1, w2, b2, out);
    }
}

// Round 9
// 219.574 us; speedup vs baseline: 2.7136x; 2.7117x over previous
//
#include <hip/hip_runtime.h>

// PGA G(3,0,1) GeometricBilinear — bf16 MFMA, 4-wave/512-reg structure (R8/R9).
// P = 16384 positions. CIN=64, 2H=256, H=128, COUT=64, 16 blades.
//
// Blade-pair packing (verified R4): for pair e (blades 2e, 2e+1):
//   X1[row = e*16+pos][k], k = s*64+i -> x[p, i, 2e+s]  (bf16 LDS, 256B rows, XOR swz)
//   even j=2e: K=64; odd j=2e+1: K=128 — weights pre-packed in d_ws (prep_w).
// MFMA 16x16x32: A=Wj (m=o), B=X1 (n=pos).
//
// R8 key insight: per-SIMD unified reg pool = 512/lane. An 8-wave block forces
// 2 waves/SIMD -> 256-reg cap -> acc[16][2](128 AGPR)+128 arch = 256, all else
// spilled (R6/R7: 437MB scratch writes; launch_bounds can't override block
// shape). Fix: 256-thread blocks (4 waves, 1 wave/SIMD, 512 regs). Each wave
// runs TWO unrolled subtasks (st=0 geo / st=1 join; phase2 jh=st). acc dies
// between subtasks; ~250 spare regs let the compiler pipeline the 96
// independent weight loads that R4 serialized (its 176us latency wall).
// R9: identical resubmit — R8 bench died on container infra, no data.

namespace {

constexpr int popc4(int v){int c=0;while(v){c+=v&1;v>>=1;}return c;}
constexpr float sgnf(int a,int b){int s=0;a>>=1;while(a){s+=popc4(a&b);a>>=1;}return (s&1)?-1.f:1.f;}

struct Tabs { float gp[16][16]; float jn[16][16]; };
constexpr Tabs mk(){
    Tabs t{};
    for(int a=0;a<16;a++)for(int b=0;b<16;b++){
        t.gp[a][b] = (a&b&1) ? 0.f : sgnf(a,b);
        if((a|b)==15){
            const int k = a&b;
            t.jn[a][b] = sgnf(a,15^a)*sgnf(b,15^b)*sgnf(15^a,15^b)*sgnf(k,15^k);
        } else t.jn[a][b] = 0.f;
    }
    return t;
}
constexpr Tabs TB = mk();
constexpr int GE[8] = {0,1,1,2,1,2,2,3};  // fallback kernel

constexpr int OFF1(int j){ return (j>>1)*49152 + ((j&1)?16384:0); }   // w1b: even 256*64, odd 256*128
constexpr int OFF2(int j){ return (j>>1)*24576 + ((j&1)?8192:0);  }   // w2b: even 64*128, odd 64*256
constexpr int W1B_ELEMS = 393216;
constexpr int W2B_ELEMS = 196608;

typedef short bf16x8 __attribute__((ext_vector_type(8)));
typedef float f32x4  __attribute__((ext_vector_type(4)));

__device__ inline unsigned short f2bf(float f){
    unsigned int u = __float_as_uint(f);
    u = u + 0x7fffu + ((u >> 16) & 1u);
    return (unsigned short)(u >> 16);
}
__device__ inline unsigned pack2(float a, float b){
    return (unsigned)f2bf(a) | ((unsigned)f2bf(b) << 16);
}

} // namespace

// ---------------- weight prep (identical to R4, verified) --------------------
__global__ void prep_w(const float* __restrict__ w1, const float* __restrict__ w2,
                       unsigned short* __restrict__ w1b, unsigned short* __restrict__ w2b)
{
    int idx = blockIdx.x * 256 + threadIdx.x;
    if (idx < W1B_ELEMS) {
        const int p = idx / 49152, rem = idx - p*49152;
        float v;
        if (rem < 16384) {                       // even j: [256 o][64 k]
            const int j = 2*p, o = rem >> 6, k = rem & 63;
            v = w1[(o*64 + k)*9 + __popc(j)];
        } else {                                 // odd j: [256 o][128 k]
            const int j = 2*p + 1, r2 = rem - 16384, o = r2 >> 7, k = r2 & 127;
            const int g = __popc(j), i = k & 63, r = (k < 64) ? g + 4 : g;
            v = w1[(o*64 + i)*9 + r];
        }
        w1b[idx] = f2bf(v);
    } else {
        idx -= W1B_ELEMS;
        if (idx < W2B_ELEMS) {
            const int p = idx / 24576, rem = idx - p*24576;
            float v;
            if (rem < 8192) {                    // even j: [64 o][128 k]
                const int j = 2*p, o = rem >> 7, k = rem & 127;
                v = w2[(o*128 + k)*9 + __popc(j)];
            } else {                             // odd j: [64 o][256 k]
                const int j = 2*p + 1, r2 = rem - 8192, o = r2 >> 8, k = r2 & 255;
                const int g = __popc(j), i = k & 127, r = (k < 128) ? g + 4 : g;
                v = w2[(o*128 + i)*9 + r];
            }
            w2b[idx] = f2bf(v);
        }
    }
}

// ---------------- fused MFMA kernel: 1024 blocks x 256 thr (4 waves) ---------
__global__ __launch_bounds__(256, 1) void gb_mfma(
    const float* __restrict__ x, const float* __restrict__ ref,
    const float* __restrict__ b1, const float* __restrict__ b2,
    const unsigned short* __restrict__ w1b, const unsigned short* __restrict__ w2b,
    float* __restrict__ out)
{
    __shared__ __attribute__((aligned(16))) char X1[32768];  // [e*16+pos][256B], swz
    __shared__ __attribute__((aligned(16))) char X2[65536];  // [e2*16+pos][512B], swz; then epilogue f32
    __shared__ float lref[16];

    const int t   = threadIdx.x;
    const int bid = blockIdx.x;
    const int w   = t >> 6;        // wave 0..3
    const int l   = t & 63;
    const int ln  = l & 15;
    const int lh  = l >> 4;
    const int swz = (ln & 7) << 4;
    const int p0  = bid * 16;

    // ---- stage X1: x[p0..p0+15][64][16] fp32 -> bf16 LDS ----
    {
        const int spos = t >> 4;           // pos 0..15
        #pragma unroll
        for (int rr = 0; rr < 2; ++rr) {
            const int i0 = (t & 15)*2 + rr*32;   // i pair (i0, i0+1)
            const float* gsrc = x + ((long)(p0 + spos))*1024 + i0*16;
            float4 v[8];
            #pragma unroll
            for (int a = 0; a < 8; ++a) v[a] = *(const float4*)(gsrc + a*4);
            const int ws_ = (spos & 7) << 4;
            #pragma unroll
            for (int b = 0; b < 16; ++b) {
                const int e = b >> 1, s = b & 1;
                const float va = ((const float*)&v[b>>2])[b&3];        // i0
                const float vb = ((const float*)&v[4 + (b>>2)])[b&3];  // i0+1
                *(unsigned*)(X1 + ((((e*16 + spos) << 8) + (s << 7) + (i0 << 1)) ^ ws_)) = pack2(va, vb);
            }
        }
        if (t < 16) lref[t] = ref[((long)(p0 + t))*16 + 15];
    }
    __syncthreads();

    // ---- phase 1 + products: two subtasks per wave (st=0 geo, st=1 join) ----
    #pragma unroll
    for (int st = 0; st < 2; ++st) {
        const int f0 = (st == 0) ? w : w + 8;
        const int oA = f0*16 + ln;
        const int oB = (f0+4)*16 + ln;

        f32x4 acc[16][2];
        #pragma unroll
        for (int j = 0; j < 16; ++j) { acc[j][0] = (f32x4)0.f; acc[j][1] = (f32x4)0.f; }

        #pragma unroll
        for (int j = 0; j < 16; ++j) {
            const int e  = j >> 1;
            const int Kj = (j & 1) ? 128 : 64;
            const unsigned short* Aj = w1b + OFF1(j);
            #pragma unroll
            for (int kf = 0; kf < ((j & 1) ? 4 : 2); ++kf) {
                const int k0 = kf*32 + lh*8;
                const bf16x8 bx = *(const bf16x8*)(X1 + ((((e*16 + ln) << 8) + (k0 << 1)) ^ swz));
                const bf16x8 a0 = *(const bf16x8*)(Aj + oA*Kj + k0);
                const bf16x8 a1 = *(const bf16x8*)(Aj + oB*Kj + k0);
                acc[j][0] = __builtin_amdgcn_mfma_f32_16x16x32_bf16(a0, bx, acc[j][0], 0, 0, 0);
                acc[j][1] = __builtin_amdgcn_mfma_f32_16x16x32_bf16(a1, bx, acc[j][1], 0, 0, 0);
            }
        }
        #pragma unroll
        for (int r = 0; r < 4; ++r) {
            acc[0][0][r] += b1[f0*16     + lh*4 + r];
            acc[0][1][r] += b1[(f0+4)*16 + lh*4 + r];
        }

        // products in-register (lane: pos=ln, 4 channels = lh*4+r)
        f32x4 prod[16];
        #pragma unroll
        for (int j = 0; j < 16; ++j) prod[j] = (f32x4)0.f;
        if (st == 0) {
            #pragma unroll
            for (int A = 0; A < 16; ++A)
                #pragma unroll
                for (int B = 0; B < 16; ++B) {
                    constexpr auto& G = TB.gp;
                    if (G[A][B] > 0.f)      prod[A ^ B] += acc[A][0] * acc[B][1];
                    else if (G[A][B] < 0.f) prod[A ^ B] -= acc[A][0] * acc[B][1];
                }
        } else {
            #pragma unroll
            for (int A = 0; A < 16; ++A)
                #pragma unroll
                for (int B = 0; B < 16; ++B) {
                    constexpr auto& J = TB.jn;
                    if (J[A][B] > 0.f)      prod[A & B] += acc[A][0] * acc[B][1];
                    else if (J[A][B] < 0.f) prod[A & B] -= acc[A][0] * acc[B][1];
                }
            const float rv = lref[ln];
            #pragma unroll
            for (int j = 0; j < 16; ++j) prod[j] *= rv;
        }

        // write prod -> X2 (4B pairs along cc). channels: st=0 -> w*16, st=1 -> 64+w*16
        const int pc0 = st*64 + w*16;
        #pragma unroll
        for (int e2 = 0; e2 < 8; ++e2)
            #pragma unroll
            for (int s = 0; s < 2; ++s)
                #pragma unroll
                for (int rp = 0; rp < 4; rp += 2) {
                    const int cc = pc0 + lh*4 + rp;
                    *(unsigned*)(X2 + ((((e2*16 + ln) << 9) + (s << 8) + (cc << 1)) ^ swz)) =
                        pack2(prod[2*e2 + s][rp], prod[2*e2 + s][rp + 1]);
                }
    }
    __syncthreads();   // all X2 writes visible

    // ---- phase 2: two subtasks (jh = st), wave owns o2 = [w*16, w*16+16) ----
    const int o2base = w * 16;
    f32x4 acc2[2][8];
    #pragma unroll
    for (int st = 0; st < 2; ++st) {
        #pragma unroll
        for (int jj = 0; jj < 8; ++jj) acc2[st][jj] = (f32x4)0.f;
        #pragma unroll
        for (int jj = 0; jj < 8; ++jj) {
            const int j2 = st*8 + jj;
            const int e2 = j2 >> 1;
            const int K2 = (j2 & 1) ? 256 : 128;
            const unsigned short* A2 = w2b + OFF2(j2);
            #pragma unroll
            for (int kf = 0; kf < ((j2 & 1) ? 8 : 4); ++kf) {
                const int k0 = kf*32 + lh*8;
                const bf16x8 bx = *(const bf16x8*)(X2 + ((((e2*16 + ln) << 9) + (k0 << 1)) ^ swz));
                const bf16x8 a  = *(const bf16x8*)(A2 + (o2base + ln)*K2 + k0);
                acc2[st][jj] = __builtin_amdgcn_mfma_f32_16x16x32_bf16(a, bx, acc2[st][jj], 0, 0, 0);
            }
        }
    }
    #pragma unroll
    for (int r = 0; r < 4; ++r) acc2[0][0][r] += b2[o2base + lh*4 + r];
    __syncthreads();   // X2 MFMA reads done; X2 becomes epilogue buffer

    // ---- epilogue: acc2 -> LDS fp32 [pos][o2][j] -> coalesced stores ----
    {
        #pragma unroll
        for (int r = 0; r < 4; ++r) {
            const int o2 = o2base + lh*4 + r;
            const int base = (ln << 12) + (o2 << 6);
            #pragma unroll
            for (int q = 0; q < 4; ++q) {
                const int jq = (q + lh) & 3;              // rotate by lh: balanced banks
                const f32x4* src = (jq < 2) ? &acc2[0][jq*4] : &acc2[1][(jq-2)*4];
                *(float4*)(X2 + ((base + (jq << 4)) ^ swz)) =
                    make_float4(src[0][r], src[1][r], src[2][r], src[3][r]);
            }
        }
    }
    __syncthreads();
    {
        #pragma unroll
        for (int it = 0; it < 16; ++it) {
            const int idx = it*256 + t;                   // 4096 float4s
            const int pos = idx >> 8, off = idx & 255;
            const float4 vv = *(const float4*)(X2 + (((pos << 12) + (off << 4)) ^ ((pos & 7) << 4)));
            *(float4*)(out + ((long)(p0 + pos))*1024 + off*4) = vv;
        }
    }
}

// ---------------- fp32 fallback (verified R3) --------------------------------
__global__ __launch_bounds__(256, 1) void gb_fused_f32(
    const float* __restrict__ x, const float* __restrict__ ref,
    const float* __restrict__ w1, const float* __restrict__ b1,
    const float* __restrict__ w2, const float* __restrict__ b2,
    float* __restrict__ out)
{
    __shared__ float lds[16384];
    __shared__ float lrefs[8];
    const int t = threadIdx.x;
    const int p0 = blockIdx.x * 8;
    {
        const float4* xg = reinterpret_cast<const float4*>(x) + (size_t)p0 * 256;
        float4* xl = reinterpret_cast<float4*>(lds);
        #pragma unroll
        for (int r = 0; r < 8; ++r) xl[r*256 + t] = xg[r*256 + t];
        if (t < 8) lrefs[t] = ref[(p0 + t)*16 + 15];
    }
    __syncthreads();
    const int c    = t & 127;
    const int half = t >> 7;
    const int ca   = (c < 64) ? c : (c + 64);
    const int cb   = ca + 64;
    float acc[4][2][16];
    #pragma unroll
    for (int q = 0; q < 4; ++q)
        #pragma unroll
        for (int s = 0; s < 2; ++s)
            #pragma unroll
            for (int j = 0; j < 16; ++j) acc[q][s][j] = 0.f;
    for (int i = 0; i < 64; ++i) {
        float wa[9], wb[9];
        #pragma unroll
        for (int r = 0; r < 9; ++r) { wa[r] = w1[(ca*64+i)*9 + r]; wb[r] = w1[(cb*64+i)*9 + r]; }
        #pragma unroll
        for (int q = 0; q < 4; ++q) {
            const float* xv = lds + (half*4 + q)*1024 + i*16;
            float xr[16];
            #pragma unroll
            for (int j4 = 0; j4 < 4; ++j4) {
                const float4 v = *reinterpret_cast<const float4*>(xv + 4*j4);
                xr[4*j4+0]=v.x; xr[4*j4+1]=v.y; xr[4*j4+2]=v.z; xr[4*j4+3]=v.w;
            }
            #pragma unroll
            for (int e = 0; e < 8; ++e) {
                const int ge = GE[e];
                const float xe = xr[2*e], xo = xr[2*e+1];
                acc[q][0][2*e]   += wa[ge]   * xe;
                acc[q][0][2*e+1] += wa[ge+1] * xo;
                acc[q][0][2*e+1] += wa[ge+5] * xe;
                acc[q][1][2*e]   += wb[ge]   * xe;
                acc[q][1][2*e+1] += wb[ge+1] * xo;
                acc[q][1][2*e+1] += wb[ge+5] * xe;
            }
        }
    }
    {
        const float ba = b1[ca], bb = b1[cb];
        #pragma unroll
        for (int q = 0; q < 4; ++q) { acc[q][0][0] += ba; acc[q][1][0] += bb; }
    }
    __syncthreads();
    #pragma unroll
    for (int q = 0; q < 4; ++q) {
        float prod[16];
        #pragma unroll
        for (int j = 0; j < 16; ++j) prod[j] = 0.f;
        if (c < 64) {
            #pragma unroll
            for (int A = 0; A < 16; ++A)
                #pragma unroll
                for (int B = 0; B < 16; ++B)
                    if (TB.gp[A][B] != 0.f)
                        prod[A ^ B] += TB.gp[A][B] * acc[q][0][A] * acc[q][1][B];
        } else {
            #pragma unroll
            for (int A = 0; A < 16; ++A)
                #pragma unroll
                for (int B = 0; B < 16; ++B)
                    if (TB.jn[A][B] != 0.f)
                        prod[A & B] += TB.jn[A][B] * acc[q][0][A] * acc[q][1][B];
            const float rp = lrefs[half*4 + q];
            #pragma unroll
            for (int j = 0; j < 16; ++j) prod[j] *= rp;
        }
        const int pos = half*4 + q;
        #pragma unroll
        for (int j4 = 0; j4 < 4; ++j4)
            *reinterpret_cast<float4*>(&lds[(pos*4 + j4)*512 + c*4]) =
                make_float4(prod[4*j4], prod[4*j4+1], prod[4*j4+2], prod[4*j4+3]);
    }
    __syncthreads();
    const int o    = t & 63;
    const int slot = t >> 6;
    float oacc[2][16];
    #pragma unroll
    for (int e2 = 0; e2 < 2; ++e2)
        #pragma unroll
        for (int j = 0; j < 16; ++j) oacc[e2][j] = 0.f;
    for (int i = 0; i < 128; ++i) {
        float wv[9];
        #pragma unroll
        for (int r = 0; r < 9; ++r) wv[r] = w2[(o*128+i)*9 + r];
        #pragma unroll
        for (int e2 = 0; e2 < 2; ++e2) {
            const int pos = slot*2 + e2;
            float xr[16];
            #pragma unroll
            for (int j4 = 0; j4 < 4; ++j4) {
                const float4 v = *reinterpret_cast<const float4*>(&lds[(pos*4 + j4)*512 + i*4]);
                xr[4*j4+0]=v.x; xr[4*j4+1]=v.y; xr[4*j4+2]=v.z; xr[4*j4+3]=v.w;
            }
            #pragma unroll
            for (int e = 0; e < 8; ++e) {
                const int ge = GE[e];
                oacc[e2][2*e]   += wv[ge]   * xr[2*e];
                oacc[e2][2*e+1] += wv[ge+1] * xr[2*e+1];
                oacc[e2][2*e+1] += wv[ge+5] * xr[2*e];
            }
        }
    }
    {
        const float bo = b2[o];
        #pragma unroll
        for (int e2 = 0; e2 < 2; ++e2) {
            oacc[e2][0] += bo;
            const int pos = p0 + slot*2 + e2;
            float* og = out + (size_t)pos*1024 + o*16;
            #pragma unroll
            for (int j4 = 0; j4 < 4; ++j4)
                *reinterpret_cast<float4*>(og + 4*j4) =
                    make_float4(oacc[e2][4*j4], oacc[e2][4*j4+1],
                                oacc[e2][4*j4+2], oacc[e2][4*j4+3]);
        }
    }
}

extern "C" void kernel_launch(void* const* d_in, const int* in_sizes, int n_in,
                              void* d_out, int out_size, void* d_ws, size_t ws_size,
                              hipStream_t stream)
{
    const float* x  = (const float*)d_in[0];
    const float* rf = (const float*)d_in[1];
    const float* w1 = (const float*)d_in[2];
    const float* b1 = (const float*)d_in[3];
    const float* w2 = (const float*)d_in[4];
    const float* b2 = (const float*)d_in[5];
    float* out = (float*)d_out;

    const size_t need = (size_t)(W1B_ELEMS + W2B_ELEMS) * sizeof(unsigned short);
    if (ws_size >= need) {
        unsigned short* w1b = (unsigned short*)d_ws;
        unsigned short* w2b = w1b + W1B_ELEMS;
        prep_w<<<(W1B_ELEMS + W2B_ELEMS)/256, 256, 0, stream>>>(w1, w2, w1b, w2b);
        gb_mfma<<<1024, 256, 0, stream>>>(x, rf, b1, b2, w1b, w2b, out);
    } else {
        gb_fused_f32<<<2048, 256, 0, stream>>>(x, rf, w1, b1, w2, b2, out);
    }
}

// Round 10
// 162.777 us; speedup vs baseline: 3.6604x; 1.3489x over previous
//
#include <hip/hip_runtime.h>

// PGA G(3,0,1) GeometricBilinear — bf16 MFMA R10: 8 waves, streamed products,
// explicit weight prefetch. P=16384, CIN=64, 2H=256, H=128, COUT=64, 16 blades.
//
// Verified mappings (R4/R9): X1[row=e*16+pos][k=s*64+i] bf16, 256B rows, XOR
// swz=(pos&7)<<4; MFMA 16x16x32 A=Wj[o][k] (o=f*16+ln... A rows = channels),
// B=X1 (cols = pos); D: lane(ln,lh) -> pos=ln, ch_in_16 = lh*4+r.
// X2[row=e2*16+pos][k2=s*128+cc] 512B rows. Epilogue: raw-then-XOR (R6 fix).
//
// R10 changes vs R9 (220us, 1 wave/SIMD, serial load->MFMA chains):
//  * 512-thr blocks (8 waves, 2/SIMD) — wave = one subtask (st=w>>2,grp=w&3).
//  * Phase 1 streaming-right: left[16] GEMM w/ 4-deep prefetch ring; right
//    blades streamed (8 regs) w/ 2-deep prefetch; product FMAs interleave.
//    Peak regs ~200 < 256 cap (R6's spill was demand ~290 at same cap).
//  * Phase 2: 1-step prefetch ring.

namespace {

constexpr int popc4(int v){int c=0;while(v){c+=v&1;v>>=1;}return c;}
constexpr float sgnf(int a,int b){int s=0;a>>=1;while(a){s+=popc4(a&b);a>>=1;}return (s&1)?-1.f:1.f;}

struct Tabs { float gp[16][16]; float jn[16][16]; };
constexpr Tabs mk(){
    Tabs t{};
    for(int a=0;a<16;a++)for(int b=0;b<16;b++){
        t.gp[a][b] = (a&b&1) ? 0.f : sgnf(a,b);
        if((a|b)==15){
            const int k = a&b;
            t.jn[a][b] = sgnf(a,15^a)*sgnf(b,15^b)*sgnf(15^a,15^b)*sgnf(k,15^k);
        } else t.jn[a][b] = 0.f;
    }
    return t;
}
constexpr Tabs TB = mk();
constexpr int GE[8] = {0,1,1,2,1,2,2,3};  // fallback kernel

constexpr int OFF1(int j){ return (j>>1)*49152 + ((j&1)?16384:0); }   // w1b: even 256*64, odd 256*128
constexpr int OFF2(int j){ return (j>>1)*24576 + ((j&1)?8192:0);  }   // w2b: even 64*128, odd 64*256
constexpr int W1B_ELEMS = 393216;
constexpr int W2B_ELEMS = 196608;

typedef short bf16x8 __attribute__((ext_vector_type(8)));
typedef float f32x4  __attribute__((ext_vector_type(4)));

__device__ inline unsigned short f2bf(float f){
    unsigned int u = __float_as_uint(f);
    u = u + 0x7fffu + ((u >> 16) & 1u);
    return (unsigned short)(u >> 16);
}
__device__ inline unsigned pack2(float a, float b){
    return (unsigned)f2bf(a) | ((unsigned)f2bf(b) << 16);
}

} // namespace

// ---------------- weight prep (identical to R4, verified) --------------------
__global__ void prep_w(const float* __restrict__ w1, const float* __restrict__ w2,
                       unsigned short* __restrict__ w1b, unsigned short* __restrict__ w2b)
{
    int idx = blockIdx.x * 256 + threadIdx.x;
    if (idx < W1B_ELEMS) {
        const int p = idx / 49152, rem = idx - p*49152;
        float v;
        if (rem < 16384) {                       // even j: [256 o][64 k]
            const int j = 2*p, o = rem >> 6, k = rem & 63;
            v = w1[(o*64 + k)*9 + __popc(j)];
        } else {                                 // odd j: [256 o][128 k]
            const int j = 2*p + 1, r2 = rem - 16384, o = r2 >> 7, k = r2 & 127;
            const int g = __popc(j), i = k & 63, r = (k < 64) ? g + 4 : g;
            v = w1[(o*64 + i)*9 + r];
        }
        w1b[idx] = f2bf(v);
    } else {
        idx -= W1B_ELEMS;
        if (idx < W2B_ELEMS) {
            const int p = idx / 24576, rem = idx - p*24576;
            float v;
            if (rem < 8192) {                    // even j: [64 o][128 k]
                const int j = 2*p, o = rem >> 7, k = rem & 127;
                v = w2[(o*128 + k)*9 + __popc(j)];
            } else {                             // odd j: [64 o][256 k]
                const int j = 2*p + 1, r2 = rem - 8192, o = r2 >> 8, k = r2 & 255;
                const int g = __popc(j), i = k & 127, r = (k < 128) ? g + 4 : g;
                v = w2[(o*128 + i)*9 + r];
            }
            w2b[idx] = f2bf(v);
        }
    }
}

// ---------------- fused MFMA kernel: 1024 blocks x 512 thr (8 waves) ---------
__global__ __launch_bounds__(512, 2) void gb_mfma(
    const float* __restrict__ x, const float* __restrict__ ref,
    const float* __restrict__ b1, const float* __restrict__ b2,
    const unsigned short* __restrict__ w1b, const unsigned short* __restrict__ w2b,
    float* __restrict__ out)
{
    __shared__ __attribute__((aligned(16))) char X1[32768];  // [e*16+pos][256B], swz
    __shared__ __attribute__((aligned(16))) char X2[65536];  // [e2*16+pos][512B], swz; then epilogue f32
    __shared__ float lref[16];

    const int t   = threadIdx.x;
    const int bid = blockIdx.x;
    const int w   = t >> 6;        // wave 0..7
    const int l   = t & 63;
    const int ln  = l & 15;
    const int lh  = l >> 4;
    const int swz = (ln & 7) << 4;
    const int p0  = bid * 16;

    const int st  = w >> 2;        // 0 = geo, 1 = join
    const int grp = w & 3;
    const int f0  = (st == 0) ? grp : grp + 8;
    const int oA  = f0*16 + ln;          // left-operand channel rows
    const int oB  = (f0+4)*16 + ln;      // right-operand channel rows

    // ---- stage X1 (verified R6/R7 prologue) ----
    {
        const int spos = t >> 5;             // pos 0..15
        const int si0  = (t & 31) * 2;       // channel pair
        const float* gsrc = x + ((long)(p0 + spos))*1024 + si0*16;
        float4 v[8];
        #pragma unroll
        for (int a = 0; a < 8; ++a) v[a] = *(const float4*)(gsrc + a*4);
        const int ws_ = (spos & 7) << 4;
        #pragma unroll
        for (int b = 0; b < 16; ++b) {
            const int e = b >> 1, s = b & 1;
            const float va = ((const float*)&v[b>>2])[b&3];
            const float vb = ((const float*)&v[4 + (b>>2)])[b&3];
            *(unsigned*)(X1 + ((((e*16 + spos) << 8) + (s << 7) + (si0 << 1)) ^ ws_)) = pack2(va, vb);
        }
        if (t < 16) lref[t] = ref[((long)(p0 + t))*16 + 15];
    }
    __syncthreads();

    // ================= phase 1: left GEMM (streamed, 4-deep prefetch) ========
    f32x4 left[16];
    #pragma unroll
    for (int j = 0; j < 16; ++j) left[j] = (f32x4)0.f;

    bf16x8 pa[4][4];   // prefetch ring: slot j&3, kf 0..3 (even j uses 2)
    #pragma unroll
    for (int jp = 0; jp < 4; ++jp) {
        const int Kj = (jp & 1) ? 128 : 64;
        const unsigned short* Aj = w1b + OFF1(jp);
        #pragma unroll
        for (int kf = 0; kf < ((jp & 1) ? 4 : 2); ++kf)
            pa[jp][kf] = *(const bf16x8*)(Aj + oA*Kj + kf*32 + lh*8);
    }
    #pragma unroll
    for (int j = 0; j < 16; ++j) {
        const int e = j >> 1, nkf = (j & 1) ? 4 : 2;
        // refill slot with j+4 BEFORE consuming (keeps 4 j's of loads in flight)
        bf16x8 cur[4];
        #pragma unroll
        for (int kf = 0; kf < nkf; ++kf) cur[kf] = pa[j & 3][kf];
        if (j < 12) {
            const int jn = j + 4, Kn = (jn & 1) ? 128 : 64;
            const unsigned short* An = w1b + OFF1(jn);
            #pragma unroll
            for (int kf = 0; kf < ((jn & 1) ? 4 : 2); ++kf)
                pa[j & 3][kf] = *(const bf16x8*)(An + oA*Kn + kf*32 + lh*8);
        }
        #pragma unroll
        for (int kf = 0; kf < nkf; ++kf) {
            const bf16x8 bx = *(const bf16x8*)(X1 + ((((e*16 + ln) << 8) + ((kf*32 + lh*8) << 1)) ^ swz));
            left[j] = __builtin_amdgcn_mfma_f32_16x16x32_bf16(cur[kf], bx, left[j], 0, 0, 0);
        }
    }
    #pragma unroll
    for (int r = 0; r < 4; ++r) left[0][r] += b1[f0*16 + lh*4 + r];

    // ======== right blades streamed + products interleaved (2-deep pf) =======
    f32x4 prod[16];
    #pragma unroll
    for (int j = 0; j < 16; ++j) prod[j] = (f32x4)0.f;

    bf16x8 pb[2][4];
    #pragma unroll
    for (int jp = 0; jp < 2; ++jp) {
        const int Kj = (jp & 1) ? 128 : 64;
        const unsigned short* Aj = w1b + OFF1(jp);
        #pragma unroll
        for (int kf = 0; kf < ((jp & 1) ? 4 : 2); ++kf)
            pb[jp][kf] = *(const bf16x8*)(Aj + oB*Kj + kf*32 + lh*8);
    }
    #pragma unroll
    for (int j = 0; j < 16; ++j) {
        const int e = j >> 1, nkf = (j & 1) ? 4 : 2;
        bf16x8 cur[4];
        #pragma unroll
        for (int kf = 0; kf < nkf; ++kf) cur[kf] = pb[j & 1][kf];
        if (j < 14) {
            const int jn = j + 2, Kn = (jn & 1) ? 128 : 64;
            const unsigned short* An = w1b + OFF1(jn);
            #pragma unroll
            for (int kf = 0; kf < ((jn & 1) ? 4 : 2); ++kf)
                pb[j & 1][kf] = *(const bf16x8*)(An + oB*Kn + kf*32 + lh*8);
        }
        f32x4 right = (f32x4)0.f;
        #pragma unroll
        for (int kf = 0; kf < nkf; ++kf) {
            const bf16x8 bx = *(const bf16x8*)(X1 + ((((e*16 + ln) << 8) + ((kf*32 + lh*8) << 1)) ^ swz));
            right = __builtin_amdgcn_mfma_f32_16x16x32_bf16(cur[kf], bx, right, 0, 0, 0);
        }
        if (j == 0) {
            #pragma unroll
            for (int r = 0; r < 4; ++r) right[r] += b1[(f0+4)*16 + lh*4 + r];
        }
        // products: column B=j against all left[A]  (VALU hides next loads)
        if (st == 0) {
            #pragma unroll
            for (int A = 0; A < 16; ++A) {
                constexpr auto& G = TB.gp;
                if (G[A][0] || true) {}   // keep A unrolled
                if (TB.gp[A][0] == TB.gp[A][0]) {}  // no-op
            }
            #pragma unroll
            for (int A = 0; A < 16; ++A) {
                if (TB.gp[A][j] > 0.f)      prod[A ^ j] += left[A] * right;
                else if (TB.gp[A][j] < 0.f) prod[A ^ j] -= left[A] * right;
            }
        } else {
            #pragma unroll
            for (int A = 0; A < 16; ++A) {
                if (TB.jn[A][j] > 0.f)      prod[A & j] += left[A] * right;
                else if (TB.jn[A][j] < 0.f) prod[A & j] -= left[A] * right;
            }
        }
    }
    if (st == 1) {
        const float rv = lref[ln];
        #pragma unroll
        for (int j = 0; j < 16; ++j) prod[j] *= rv;
    }

    // ---- write prod -> X2 (4B pairs, verified R9 layout) ----
    {
        const int pc0 = st*64 + grp*16;
        #pragma unroll
        for (int e2 = 0; e2 < 8; ++e2)
            #pragma unroll
            for (int s = 0; s < 2; ++s)
                #pragma unroll
                for (int rp = 0; rp < 4; rp += 2) {
                    const int cc = pc0 + lh*4 + rp;
                    *(unsigned*)(X2 + ((((e2*16 + ln) << 9) + (s << 8) + (cc << 1)) ^ swz)) =
                        pack2(prod[2*e2 + s][rp], prod[2*e2 + s][rp + 1]);
                }
    }
    __syncthreads();   // X2 visible

    // ================= phase 2: wave = (st blades)x(grp o2), 1-step pf =======
    const int o2base = grp * 16;
    f32x4 acc2[8];
    #pragma unroll
    for (int jj = 0; jj < 8; ++jj) acc2[jj] = (f32x4)0.f;

    bf16x8 pc[2][8];
    {
        const int j2 = st*8, K2 = (j2 & 1) ? 256 : 128;
        const unsigned short* A2 = w2b + OFF2(j2);
        #pragma unroll
        for (int kf = 0; kf < ((j2 & 1) ? 8 : 4); ++kf)
            pc[0][kf] = *(const bf16x8*)(A2 + (o2base + ln)*K2 + kf*32 + lh*8);
    }
    #pragma unroll
    for (int jj = 0; jj < 8; ++jj) {
        const int j2 = st*8 + jj, e2 = j2 >> 1, nkf = (j2 & 1) ? 8 : 4;
        bf16x8 cur[8];
        #pragma unroll
        for (int kf = 0; kf < nkf; ++kf) cur[kf] = pc[jj & 1][kf];
        if (jj < 7) {
            const int jn = st*8 + jj + 1, Kn = (jn & 1) ? 256 : 128;
            const unsigned short* An = w2b + OFF2(jn);
            #pragma unroll
            for (int kf = 0; kf < ((jn & 1) ? 8 : 4); ++kf)
                pc[(jj + 1) & 1][kf] = *(const bf16x8*)(An + (o2base + ln)*Kn + kf*32 + lh*8);
        }
        #pragma unroll
        for (int kf = 0; kf < nkf; ++kf) {
            const bf16x8 bx = *(const bf16x8*)(X2 + ((((e2*16 + ln) << 9) + ((kf*32 + lh*8) << 1)) ^ swz));
            acc2[jj] = __builtin_amdgcn_mfma_f32_16x16x32_bf16(cur[kf], bx, acc2[jj], 0, 0, 0);
        }
    }
    if (st == 0) {
        #pragma unroll
        for (int r = 0; r < 4; ++r) acc2[0][r] += b2[o2base + lh*4 + r];
    }
    __syncthreads();   // X2 MFMA reads done; X2 becomes epilogue buffer

    // ---- epilogue (verified R6 fixed version): raw-then-XOR ----
    {
        #pragma unroll
        for (int r = 0; r < 4; ++r) {
            const int o2 = o2base + lh*4 + r;
            const int raw0 = (ln << 12) + (o2 << 6) + (st << 5);
            *(float4*)(X2 + (raw0 ^ swz)) =
                make_float4(acc2[0][r], acc2[1][r], acc2[2][r], acc2[3][r]);
            *(float4*)(X2 + ((raw0 + 16) ^ swz)) =
                make_float4(acc2[4][r], acc2[5][r], acc2[6][r], acc2[7][r]);
        }
    }
    __syncthreads();
    {
        #pragma unroll
        for (int it = 0; it < 8; ++it) {
            const int idx = it*512 + t;                   // 4096 float4s
            const int pos = idx >> 8, off = idx & 255;
            const float4 vv = *(const float4*)(X2 + (((pos << 12) + (off << 4)) ^ ((pos & 7) << 4)));
            *(float4*)(out + ((long)(p0 + pos))*1024 + off*4) = vv;
        }
    }
}

// ---------------- fp32 fallback (verified R3) --------------------------------
__global__ __launch_bounds__(256, 1) void gb_fused_f32(
    const float* __restrict__ x, const float* __restrict__ ref,
    const float* __restrict__ w1, const float* __restrict__ b1,
    const float* __restrict__ w2, const float* __restrict__ b2,
    float* __restrict__ out)
{
    __shared__ float lds[16384];
    __shared__ float lrefs[8];
    const int t = threadIdx.x;
    const int p0 = blockIdx.x * 8;
    {
        const float4* xg = reinterpret_cast<const float4*>(x) + (size_t)p0 * 256;
        float4* xl = reinterpret_cast<float4*>(lds);
        #pragma unroll
        for (int r = 0; r < 8; ++r) xl[r*256 + t] = xg[r*256 + t];
        if (t < 8) lrefs[t] = ref[(p0 + t)*16 + 15];
    }
    __syncthreads();
    const int c    = t & 127;
    const int half = t >> 7;
    const int ca   = (c < 64) ? c : (c + 64);
    const int cb   = ca + 64;
    float acc[4][2][16];
    #pragma unroll
    for (int q = 0; q < 4; ++q)
        #pragma unroll
        for (int s = 0; s < 2; ++s)
            #pragma unroll
            for (int j = 0; j < 16; ++j) acc[q][s][j] = 0.f;
    for (int i = 0; i < 64; ++i) {
        float wa[9], wb[9];
        #pragma unroll
        for (int r = 0; r < 9; ++r) { wa[r] = w1[(ca*64+i)*9 + r]; wb[r] = w1[(cb*64+i)*9 + r]; }
        #pragma unroll
        for (int q = 0; q < 4; ++q) {
            const float* xv = lds + (half*4 + q)*1024 + i*16;
            float xr[16];
            #pragma unroll
            for (int j4 = 0; j4 < 4; ++j4) {
                const float4 v = *reinterpret_cast<const float4*>(xv + 4*j4);
                xr[4*j4+0]=v.x; xr[4*j4+1]=v.y; xr[4*j4+2]=v.z; xr[4*j4+3]=v.w;
            }
            #pragma unroll
            for (int e = 0; e < 8; ++e) {
                const int ge = GE[e];
                const float xe = xr[2*e], xo = xr[2*e+1];
                acc[q][0][2*e]   += wa[ge]   * xe;
                acc[q][0][2*e+1] += wa[ge+1] * xo;
                acc[q][0][2*e+1] += wa[ge+5] * xe;
                acc[q][1][2*e]   += wb[ge]   * xe;
                acc[q][1][2*e+1] += wb[ge+1] * xo;
                acc[q][1][2*e+1] += wb[ge+5] * xe;
            }
        }
    }
    {
        const float ba = b1[ca], bb = b1[cb];
        #pragma unroll
        for (int q = 0; q < 4; ++q) { acc[q][0][0] += ba; acc[q][1][0] += bb; }
    }
    __syncthreads();
    #pragma unroll
    for (int q = 0; q < 4; ++q) {
        float prod[16];
        #pragma unroll
        for (int j = 0; j < 16; ++j) prod[j] = 0.f;
        if (c < 64) {
            #pragma unroll
            for (int A = 0; A < 16; ++A)
                #pragma unroll
                for (int B = 0; B < 16; ++B)
                    if (TB.gp[A][B] != 0.f)
                        prod[A ^ B] += TB.gp[A][B] * acc[q][0][A] * acc[q][1][B];
        } else {
            #pragma unroll
            for (int A = 0; A < 16; ++A)
                #pragma unroll
                for (int B = 0; B < 16; ++B)
                    if (TB.jn[A][B] != 0.f)
                        prod[A & B] += TB.jn[A][B] * acc[q][0][A] * acc[q][1][B];
            const float rp = lrefs[half*4 + q];
            #pragma unroll
            for (int j = 0; j < 16; ++j) prod[j] *= rp;
        }
        const int pos = half*4 + q;
        #pragma unroll
        for (int j4 = 0; j4 < 4; ++j4)
            *reinterpret_cast<float4*>(&lds[(pos*4 + j4)*512 + c*4]) =
                make_float4(prod[4*j4], prod[4*j4+1], prod[4*j4+2], prod[4*j4+3]);
    }
    __syncthreads();
    const int o    = t & 63;
    const int slot = t >> 6;
    float oacc[2][16];
    #pragma unroll
    for (int e2 = 0; e2 < 2; ++e2)
        #pragma unroll
        for (int j = 0; j < 16; ++j) oacc[e2][j] = 0.f;
    for (int i = 0; i < 128; ++i) {
        float wv[9];
        #pragma unroll
        for (int r = 0; r < 9; ++r) wv[r] = w2[(o*128+i)*9 + r];
        #pragma unroll
        for (int e2 = 0; e2 < 2; ++e2) {
            const int pos = slot*2 + e2;
            float xr[16];
            #pragma unroll
            for (int j4 = 0; j4 < 4; ++j4) {
                const float4 v = *reinterpret_cast<const float4*>(&lds[(pos*4 + j4)*512 + i*4]);
                xr[4*j4+0]=v.x; xr[4*j4+1]=v.y; xr[4*j4+2]=v.z; xr[4*j4+3]=v.w;
            }
            #pragma unroll
            for (int e = 0; e < 8; ++e) {
                const int ge = GE[e];
                oacc[e2][2*e]   += wv[ge]   * xr[2*e];
                oacc[e2][2*e+1] += wv[ge+1] * xr[2*e+1];
                oacc[e2][2*e+1] += wv[ge+5] * xr[2*e];
            }
        }
    }
    {
        const float bo = b2[o];
        #pragma unroll
        for (int e2 = 0; e2 < 2; ++e2) {
            oacc[e2][0] += bo;
            const int pos = p0 + slot*2 + e2;
            float* og = out + (size_t)pos*1024 + o*16;
            #pragma unroll
            for (int j4 = 0; j4 < 4; ++j4)
                *reinterpret_cast<float4*>(og + 4*j4) =
                    make_float4(oacc[e2][4*j4], oacc[e2][4*j4+1],
                                oacc[e2][4*j4+2], oacc[e2][4*j4+3]);
        }
    }
}

extern "C" void kernel_launch(void* const* d_in, const int* in_sizes, int n_in,
                              void* d_out, int out_size, void* d_ws, size_t ws_size,
                              hipStream_t stream)
{
    const float* x  = (const float*)d_in[0];
    const float* rf = (const float*)d_in[1];
    const float* w1 = (const float*)d_in[2];
    const float* b1 = (const float*)d_in[3];
    const float* w2 = (const float*)d_in[4];
    const float* b2 = (const float*)d_in[5];
    float* out = (float*)d_out;

    const size_t need = (size_t)(W1B_ELEMS + W2B_ELEMS) * sizeof(unsigned short);
    if (ws_size >= need) {
        unsigned short* w1b = (unsigned short*)d_ws;
        unsigned short* w2b = w1b + W1B_ELEMS;
        prep_w<<<(W1B_ELEMS + W2B_ELEMS)/256, 256, 0, stream>>>(w1, w2, w1b, w2b);
        gb_mfma<<<1024, 512, 0, stream>>>(x, rf, b1, b2, w1b, w2b, out);
    } else {
        gb_fused_f32<<<2048, 256, 0, stream>>>(x, rf, w1, b1, w2, b2, out);
    }
}